// Round 7
// baseline (139.891 us; speedup 1.0000x reference)
//
#include <hip/hip_runtime.h>

using f32x4  = __attribute__((ext_vector_type(4))) float;
using u16x8  = __attribute__((ext_vector_type(8))) unsigned short;
using u16x4  = __attribute__((ext_vector_type(4))) unsigned short;
using bf16x8 = __attribute__((ext_vector_type(8))) __bf16;

__device__ __forceinline__ unsigned short f2bf(float f){
  unsigned int u = __builtin_bit_cast(unsigned int, f);
  u += 0x7fffu + ((u >> 16) & 1u);          // RNE to bf16
  return (unsigned short)(u >> 16);
}
__device__ __forceinline__ float bf2f(unsigned short h){
  return __builtin_bit_cast(float, ((unsigned int)h) << 16);
}
__device__ __forceinline__ unsigned short f2h(float f){
  return __builtin_bit_cast(unsigned short, (_Float16)f);
}
__device__ __forceinline__ float h2f(unsigned short h){
  return (float)__builtin_bit_cast(_Float16, h);
}
__device__ __forceinline__ f32x4 mfma_bf16(u16x8 a, u16x8 b, f32x4 c){
  return __builtin_amdgcn_mfma_f32_16x16x32_bf16(
      __builtin_bit_cast(bf16x8, a), __builtin_bit_cast(bf16x8, b), c, 0, 0, 0);
}
__device__ __forceinline__ float fast_sigmoid(float x){
  return __builtin_amdgcn_rcpf(1.0f + __builtin_amdgcn_exp2f(-1.44269504f * x));
}

constexpr int C_  = 256;
constexpr int L_  = 64;
constexpr int CHW = C_ * 64;   // 16384

#define LGKM0()    asm volatile("s_waitcnt lgkmcnt(0)" ::: "memory")
#define MEMFENCE() asm volatile("" ::: "memory")

__device__ __forceinline__ void poll4(const volatile int* f, int tgt){
  int n = 0;
  while (f[0] < tgt || f[1] < tgt || f[2] < tgt || f[3] < tgt){
    if (++n > (1 << 24)) break;   // safety: garbage instead of hang
  }
  MEMFENCE();
}
__device__ __forceinline__ void poll1(const volatile int* f, int tgt){
  int n = 0;
  while (f[0] < tgt){
    if (++n > (1 << 24)) break;
  }
  MEMFENCE();
}

// LDS operand layout (bf16/fp16, 256 c x 16 p): el(c,p) = ((c>>3)*16 + p)*8 + (c&7)
// B-fragment (kc, lane): b128 at kc*512 + (lane>>4)*128 + (lane&15)*8
// staging: b128 at (octet*16 + pixel)*8 ; epilogue rows ro..ro+3: b64 at
// ((ro>>3)*16 + m)*8 + (ro&7)
//
// Flag protocol (monotone LDS flags, single writer each):
//   sflag[rw]  : P-wave rw finished step l (state s_l written)
//   gsflag[rw] : G-wave rw staged z_j AND z_{j+1}
//   kflag[rw]  : G-wave rw published k_jc (implies all z_jc staged, via gsflag poll)
// Ring depth 4 (zbuf, kbuf); reuse gated by sflag >= j-3.

__global__ __launch_bounds__(512, 2)
void kalman_kernel(const float* __restrict__ z,  const float* __restrict__ Wg,
                   const float* __restrict__ bg, const float* __restrict__ Wp,
                   const float* __restrict__ bp, float* __restrict__ out)
{
  __shared__ unsigned short zbuf[4][4096];   // z ring
  __shared__ unsigned short sbuf[2][4096];   // state ping-pong (bf16)
  __shared__ unsigned short kbuf[4][4096];   // gain ring (fp16)
  __shared__ int flg[16];                    // 0..3 sflag, 4..7 gsflag, 8..11 kflag

  // XCD swizzle: q-siblings of one b share an XCD's L2
  const int lx  = (int)blockIdx.x;
  const int b   = (lx & 7) + 8 * ((lx >> 3) >> 2);
  const int q   = (lx >> 3) & 3;

  const int t    = (int)threadIdx.x;
  const int lane = t & 63;
  const int wv   = t >> 6;
  const int role = wv >> 2;           // 0 = P (recurrence), 1 = G (gain producer)
  const int rw   = wv & 3;            // owns M-tiles rw*4 .. rw*4+3 (rows rw*64..+63)
  const int m    = lane & 15;
  const int g    = lane >> 4;

  const float* zg = z + (size_t)b * L_ * CHW + q * 16;

  // ---- per-role weights: 4 M-tiles x 8 K-chunks in regs (scalar RNE cvt) ----
  const float* Wsel = (role == 0) ? Wp : Wg;
  const float* bsrc = (role == 0) ? bp : bg;
  u16x8 wf[4][8];
  f32x4 bsel[4];
  #pragma unroll
  for (int mi = 0; mi < 4; ++mi){
    const int mt = rw * 4 + mi;
    const float* src = Wsel + (size_t)(mt * 16 + m) * 256 + g * 8;
    #pragma unroll
    for (int kc = 0; kc < 8; ++kc){
      f32x4 a0 = *(const f32x4*)(src + kc * 32);
      f32x4 a1 = *(const f32x4*)(src + kc * 32 + 4);
      #pragma unroll
      for (int j = 0; j < 4; ++j){
        wf[mi][kc][j]     = f2bf(a0[j]);
        wf[mi][kc][j + 4] = f2bf(a1[j]);
      }
    }
    bsel[mi] = *(const f32x4*)(bsrc + mt * 16 + g * 4);
  }

  // ---- prologue: s_0 = z_0 staged by ALL threads ----
  {
    const int sp = t & 15;
    const int ss = t >> 4;
    const float* s0 = zg + ss * 8 * 64 + sp;
    float v[8];
    #pragma unroll
    for (int j = 0; j < 8; ++j) v[j] = s0[j * 64];
    u16x8 u;
    #pragma unroll
    for (int j = 0; j < 8; ++j) u[j] = f2bf(v[j]);
    *(u16x8*)(&sbuf[0][(ss * 16 + sp) * 8]) = u;
  }

  // ---- G prefetch ids + initial issue (z_1 -> pfA, z_2 -> pfB) ----
  const int sp2 = lane & 15;
  const int so2 = rw * 4 + (lane >> 4);          // octets so2 and so2+16
  const float* zsrc0 = zg + so2 * 8 * 64 + sp2;
  const float* zsrc1 = zg + (so2 + 16) * 8 * 64 + sp2;
  float pfA0[8], pfA1[8], pfB0[8], pfB1[8];
  if (role == 1){
    #pragma unroll
    for (int i = 0; i < 8; ++i){
      pfA0[i] = zsrc0[CHW + i * 64];     pfA1[i] = zsrc1[CHW + i * 64];
      pfB0[i] = zsrc0[2 * CHW + i * 64]; pfB1[i] = zsrc1[2 * CHW + i * 64];
    }
  }

  if (t < 16) flg[t] = 0;
  __syncthreads();

  const int boff = g * 128 + m * 8;
  volatile int* sflag  = (volatile int*)flg;
  volatile int* gsflag = (volatile int*)(flg + 4);
  volatile int* kflag  = (volatile int*)(flg + 8);

  if (role == 1){
    // ================= G: free-running gain producer =================
    for (int j = 1; j < 64; j += 2){
      poll4(sflag, j - 3);                       // ring back-pressure

      // commit z_j (pfA) and z_{j+1} (pfB) -> zbuf ring (scalar RNE pack)
      {
        u16x8 u0, u1;
        #pragma unroll
        for (int i = 0; i < 8; ++i){ u0[i] = f2bf(pfA0[i]); u1[i] = f2bf(pfA1[i]); }
        *(u16x8*)(&zbuf[j & 3][(so2 * 16 + sp2) * 8]) = u0;
        *(u16x8*)(&zbuf[j & 3][((so2 + 16) * 16 + sp2) * 8]) = u1;
      }
      if (j + 1 < 64){
        u16x8 u0, u1;
        #pragma unroll
        for (int i = 0; i < 8; ++i){ u0[i] = f2bf(pfB0[i]); u1[i] = f2bf(pfB1[i]); }
        *(u16x8*)(&zbuf[(j + 1) & 3][(so2 * 16 + sp2) * 8]) = u0;
        *(u16x8*)(&zbuf[(j + 1) & 3][((so2 + 16) * 16 + sp2) * 8]) = u1;
      }
      LGKM0();
      if (lane == 0) gsflag[rw] = j;
      poll4(gsflag, j);                          // all G staged z_j, z_{j+1}

      // issue next superstep's loads (covered by 2 matvecs + sigmoids)
      if (j + 2 < 64){
        const float* s0 = zsrc0 + (size_t)(j + 2) * CHW;
        const float* s1 = zsrc1 + (size_t)(j + 2) * CHW;
        #pragma unroll
        for (int i = 0; i < 8; ++i){ pfA0[i] = s0[i * 64]; pfA1[i] = s1[i * 64]; }
      }
      if (j + 3 < 64){
        const float* s0 = zsrc0 + (size_t)(j + 3) * CHW;
        const float* s1 = zsrc1 + (size_t)(j + 3) * CHW;
        #pragma unroll
        for (int i = 0; i < 8; ++i){ pfB0[i] = s0[i * 64]; pfB1[i] = s1[i * 64]; }
      }

      // gain matvecs for j and j+1
      #pragma unroll
      for (int jj = 0; jj < 2; ++jj){
        const int jc = j + jj;
        if (jc > 63) break;
        const unsigned short* zb = zbuf[jc & 3];
        u16x8 zf[8];
        #pragma unroll
        for (int kc = 0; kc < 8; ++kc) zf[kc] = *(const u16x8*)(zb + kc * 512 + boff);
        f32x4 gl[4] = {bsel[0], bsel[1], bsel[2], bsel[3]};   // bias in acc init
        #pragma unroll
        for (int kc = 0; kc < 8; ++kc)
          #pragma unroll
          for (int mi = 0; mi < 4; ++mi)
            gl[mi] = mfma_bf16(wf[mi][kc], zf[kc], gl[mi]);
        #pragma unroll
        for (int mi = 0; mi < 4; ++mi){
          const int ro = (rw * 4 + mi) * 16 + g * 4;
          const int el = ((ro >> 3) * 16 + m) * 8 + (ro & 7);
          u16x4 kk;
          #pragma unroll
          for (int r = 0; r < 4; ++r) kk[r] = f2h(fast_sigmoid(gl[mi][r]));
          *(u16x4*)(&kbuf[jc & 3][el]) = kk;
        }
        LGKM0();
        if (lane == 0) kflag[rw] = jc;
      }
    }
  } else {
    // ================= P: lean recurrence consumer =================
    for (int l = 1; l < 63; ++l){
      poll4(sflag, l - 1);                 // state s_{l-1} complete (all P-waves)
      poll1(kflag + rw, l);                // k_l + z_l ready (own rows; z via gsflag chain)

      const unsigned short* sb = sbuf[(l - 1) & 1];
      const unsigned short* zb = zbuf[l & 3];
      const unsigned short* kb = kbuf[l & 3];

      u16x4 zi4[4], k4[4];
      #pragma unroll
      for (int mi = 0; mi < 4; ++mi){
        const int ro = (rw * 4 + mi) * 16 + g * 4;
        const int el = ((ro >> 3) * 16 + m) * 8 + (ro & 7);
        zi4[mi] = *(const u16x4*)(zb + el);
        k4[mi]  = *(const u16x4*)(kb + el);
      }
      u16x8 sf[8];
      #pragma unroll
      for (int kc = 0; kc < 8; ++kc) sf[kc] = *(const u16x8*)(sb + kc * 512 + boff);

      f32x4 zpA[4] = {bsel[0], bsel[1], bsel[2], bsel[3]};    // bias in acc init
      f32x4 zpB[4] = {{0,0,0,0},{0,0,0,0},{0,0,0,0},{0,0,0,0}};
      __builtin_amdgcn_s_setprio(1);
      #pragma unroll
      for (int kc = 0; kc < 4; ++kc)
        #pragma unroll
        for (int mi = 0; mi < 4; ++mi){
          zpA[mi] = mfma_bf16(wf[mi][kc],     sf[kc],     zpA[mi]);
          zpB[mi] = mfma_bf16(wf[mi][kc + 4], sf[kc + 4], zpB[mi]);
        }
      __builtin_amdgcn_s_setprio(0);

      unsigned short* sbw = sbuf[l & 1];
      #pragma unroll
      for (int mi = 0; mi < 4; ++mi){
        const int ro = (rw * 4 + mi) * 16 + g * 4;
        const int el = ((ro >> 3) * 16 + m) * 8 + (ro & 7);
        u16x4 sh;
        #pragma unroll
        for (int r = 0; r < 4; ++r){
          float zpr = zpA[mi][r] + zpB[mi][r];
          float zh  = zpr + h2f(k4[mi][r]) * (bf2f(zi4[mi][r]) - zpr);
          sh[r] = f2bf(zh);
        }
        *(u16x4*)(sbw + el) = sh;
      }
      LGKM0();
      if (lane == 0) sflag[rw] = l;
    }

    // ---- peeled final step l = 63: out (f32) from regs ----
    poll4(sflag, 62);
    poll1(kflag + rw, 63);

    const unsigned short* sb = sbuf[0];          // s_62  ((63-1)&1)
    const unsigned short* zb = zbuf[3];          // z_63  (63&3)
    const unsigned short* kb = kbuf[3];          // k_63  (63&3)

    u16x4 zi4[4], k4[4];
    #pragma unroll
    for (int mi = 0; mi < 4; ++mi){
      const int ro = (rw * 4 + mi) * 16 + g * 4;
      const int el = ((ro >> 3) * 16 + m) * 8 + (ro & 7);
      zi4[mi] = *(const u16x4*)(zb + el);
      k4[mi]  = *(const u16x4*)(kb + el);
    }
    u16x8 sf[8];
    #pragma unroll
    for (int kc = 0; kc < 8; ++kc) sf[kc] = *(const u16x8*)(sb + kc * 512 + boff);

    f32x4 zpA[4] = {bsel[0], bsel[1], bsel[2], bsel[3]};
    f32x4 zpB[4] = {{0,0,0,0},{0,0,0,0},{0,0,0,0},{0,0,0,0}};
    #pragma unroll
    for (int kc = 0; kc < 4; ++kc)
      #pragma unroll
      for (int mi = 0; mi < 4; ++mi){
        zpA[mi] = mfma_bf16(wf[mi][kc],     sf[kc],     zpA[mi]);
        zpB[mi] = mfma_bf16(wf[mi][kc + 4], sf[kc + 4], zpB[mi]);
      }

    #pragma unroll
    for (int mi = 0; mi < 4; ++mi){
      const int ro = (rw * 4 + mi) * 16 + g * 4;
      float* o = out + ((size_t)b * 256 + ro) * 64 + q * 16 + m;
      #pragma unroll
      for (int r = 0; r < 4; ++r){
        float zpr = zpA[mi][r] + zpB[mi][r];
        o[r * 64] = zpr + h2f(k4[mi][r]) * (bf2f(zi4[mi][r]) - zpr);
      }
    }
  }
}

extern "C" void kernel_launch(void* const* d_in, const int* in_sizes, int n_in,
                              void* d_out, int out_size, void* d_ws, size_t ws_size,
                              hipStream_t stream)
{
  const float* z  = (const float*)d_in[0];
  const float* Wg = (const float*)d_in[1];
  const float* bg = (const float*)d_in[2];
  const float* Wp = (const float*)d_in[3];
  const float* bp = (const float*)d_in[4];
  float* out = (float*)d_out;
  hipLaunchKernelGGL(kalman_kernel, dim3(256), dim3(512), 0, stream,
                     z, Wg, bg, Wp, bp, out);
}